// Round 6
// baseline (289.975 us; speedup 1.0000x reference)
//
#include <hip/hip_runtime.h>
#include <math.h>

#define TLEN 2048
#define BSZ  4
#define EDIM 768
#define NH   12
#define HD   64
#define NBH  (BSZ * NH)
#define LOG2E 1.44269504088896f

typedef __bf16 bf16;
typedef __bf16 bf16x8 __attribute__((ext_vector_type(8)));
typedef float  f32x4  __attribute__((ext_vector_type(4)));
typedef unsigned int uint;

__device__ __forceinline__ f32x4 mfma16(bf16x8 a, bf16x8 b, f32x4 c) {
  return __builtin_amdgcn_mfma_f32_16x16x32_bf16(a, b, c, 0, 0, 0);
}

__device__ __forceinline__ uint cvtpk(float lo, float hi) {
  uint r;
  asm("v_cvt_pk_bf16_f32 %0, %1, %2" : "=v"(r) : "v"(lo), "v"(hi));
  return r;
}

// async global->LDS 16B (dest = wave-uniform base + lane*16; source per-lane)
#define GLD16(gp, lp)                                                          \
  __builtin_amdgcn_global_load_lds(                                            \
      (const __attribute__((address_space(1))) uint32_t*)(gp),                 \
      (__attribute__((address_space(3))) uint32_t*)(lp), 16, 0, 0)

// swizzled LDS fragment read: tile rows of 128B, XOR bits 4-6 with row&7
__device__ __forceinline__ bf16x8 ldsfrag(const bf16* t, int row, int kb) {
  return *reinterpret_cast<const bf16x8*>(
      (const char*)t + row * 128 + (kb ^ ((row & 7) << 4)));
}

// 8B variant (stays within one 16B swizzle chunk for 8B-aligned kb)
__device__ __forceinline__ uint2 ldsfrag64(const bf16* t, int row, int kb) {
  return *reinterpret_cast<const uint2*>(
      (const char*)t + row * 128 + (kb ^ ((row & 7) << 4)));
}

// ---------------- workspace layout (bytes) ----------------
#define CT_OFF   0x0u
#define ST_OFF   0x40000u
#define FLG_OFF  0x80000u
#define AQ_OFF   0x100000u   // query bf16; reused as VT after gemm0
#define VT_OFF   0x100000u
#define QB_OFF   0xD00000u
#define KB_OFF   0x1900000u
#define VB_OFF   0x2500000u  // reused as XB after vtrans
#define XB_OFF   0x2500000u
#define WI_OFF   0x3100000u
#define WO_OFF   0x3460000u

#define QN8  786432   // 2048*4*768/8
#define WIN8 221184   // 2304*768/8
#define WON8 73728    // 768*768/8

__device__ __forceinline__ void cvt8(const float* __restrict__ s,
                                     bf16* __restrict__ d, int i) {
  const float4* sp = reinterpret_cast<const float4*>(s) + (size_t)i * 2;
  float4 a = sp[0], b = sp[1];
  bf16x8 o;
  o[0] = (bf16)a.x; o[1] = (bf16)a.y; o[2] = (bf16)a.z; o[3] = (bf16)a.w;
  o[4] = (bf16)b.x; o[5] = (bf16)b.y; o[6] = (bf16)b.z; o[7] = (bf16)b.w;
  reinterpret_cast<bf16x8*>(d)[i] = o;
}

// ---------------- fused prep: rope tables + fp32->bf16 cvt + mask flags -------
__global__ __launch_bounds__(256) void prep_all_kernel(
    const float* __restrict__ q, bf16* __restrict__ qo,
    const float* __restrict__ wi, bf16* __restrict__ wio,
    const float* __restrict__ wo, bf16* __restrict__ woo,
    const float* __restrict__ mask, uint* __restrict__ flags,
    float* __restrict__ ct, float* __restrict__ st) {
  int bid = blockIdx.x;
  int tid = threadIdx.x;
  if (bid < 256) {
    int i = bid * 256 + tid;               // TLEN*32 table entries
    int t = i >> 5, j = i & 31;
    double ang = (double)t * pow(10000.0, -(double)j / 32.0);
    st[i] = (float)sin(ang);
    ct[i] = (float)cos(ang);
  } else if (bid < 4480) {
    int i = (bid - 256) * 256 + tid;
    if (i < QN8) { cvt8(q, qo, i); return; }
    int j = i - QN8;
    if (j < WIN8) { cvt8(wi, wio, j); return; }
    cvt8(wo, woo, j - WIN8);
  } else {
    int tile = bid - 4480;                 // 0..1023
    int ty = tile >> 5, tx = tile & 31;
    uint acc = 0;
#pragma unroll
    for (int i = 0; i < 4; ++i) {
      int c = tid + 256 * i;
      int rr = c >> 4, cc = (c & 15) * 4;
      float4 v = *reinterpret_cast<const float4*>(
          mask + (size_t)(ty * 64 + rr) * TLEN + tx * 64 + cc);
      acc |= __float_as_uint(v.x) | __float_as_uint(v.y) |
             __float_as_uint(v.z) | __float_as_uint(v.w);
    }
    unsigned long long b = __ballot(acc != 0);
    __shared__ uint red[4];
    if ((tid & 63) == 0) red[tid >> 6] = (b != 0ull) ? 1u : 0u;
    __syncthreads();
    if (tid == 0) flags[tile] = red[0] | red[1] | red[2] | red[3];
  }
}

// ---------------- V transpose: [bh][t][d] -> [bh][d][t], register 8x8 ---------
__global__ __launch_bounds__(256) void vtrans_kernel(const bf16* __restrict__ v,
                                                     bf16* __restrict__ vt) {
  int w = threadIdx.x >> 6, lane = threadIdx.x & 63;
  int bh = blockIdx.y;
  int t0 = (blockIdx.x * 4 + w) * 64;
  const bf16* src = v + ((size_t)bh * TLEN + t0) * HD;
  bf16* dst = vt + (size_t)bh * HD * TLEN + t0;
  int d0 = (lane & 7) * 8, tr = (lane >> 3) * 8;
  bf16x8 in[8];
#pragma unroll
  for (int r = 0; r < 8; ++r)
    in[r] = *reinterpret_cast<const bf16x8*>(src + (size_t)(tr + r) * HD + d0);
  bf16x8 out[8];
#pragma unroll
  for (int j = 0; j < 8; ++j)
#pragma unroll
    for (int r = 0; r < 8; ++r) out[j][r] = in[r][j];
#pragma unroll
  for (int j = 0; j < 8; ++j)
    *reinterpret_cast<bf16x8*>(dst + (size_t)(d0 + j) * TLEN + tr) = out[j];
}

// ---------------- GEMM C = A * B^T (+bias), bf16 in, 128x128 tile, BK=64 ------
template <int MODE>
__global__ __launch_bounds__(256) void gemm_bt(
    const bf16* __restrict__ A, const bf16* __restrict__ B,
    const float* __restrict__ bias,
    const float* __restrict__ ct, const float* __restrict__ st,
    bf16* __restrict__ qo, bf16* __restrict__ ko, bf16* __restrict__ vo,
    float* __restrict__ fo) {
  constexpr int K = EDIM;
  __shared__ __align__(16) bf16 As[128 * 64];
  __shared__ __align__(16) bf16 Bs[128 * 64];
  int tid = threadIdx.x;
  int lane = tid & 63, w = tid >> 6;
  int wr = w >> 1, wc = w & 1;
  int g = lane >> 4, cl = lane & 15;
  int bm = blockIdx.y, bn = blockIdx.x;
  int lrow = lane >> 3;
  int colb = ((lane & 7) ^ lrow) << 4;
  const char* Abase = (const char*)(A + (size_t)bm * 128 * K);
  const char* Bbase = (const char*)(B + (size_t)bn * 128 * K);

  f32x4 acc[4][4] = {};

  for (int kt = 0; kt < K; kt += 64) {
#pragma unroll
    for (int i = 0; i < 4; ++i) {
      int qi = w * 4 + i;
      int row = qi * 8 + lrow;
      GLD16(Abase + (size_t)row * (K * 2) + kt * 2 + colb, As + qi * 512 + lane * 8);
      GLD16(Bbase + (size_t)row * (K * 2) + kt * 2 + colb, Bs + qi * 512 + lane * 8);
    }
    __syncthreads();
#pragma unroll
    for (int kk = 0; kk < 2; ++kk) {
      bf16x8 af[4], bfr[4];
#pragma unroll
      for (int mi = 0; mi < 4; ++mi)
        af[mi] = ldsfrag(As, wr * 64 + mi * 16 + cl, kk * 64 + g * 16);
#pragma unroll
      for (int ni = 0; ni < 4; ++ni)
        bfr[ni] = ldsfrag(Bs, wc * 64 + ni * 16 + cl, kk * 64 + g * 16);
#pragma unroll
      for (int mi = 0; mi < 4; ++mi)
#pragma unroll
        for (int ni = 0; ni < 4; ++ni)
          acc[mi][ni] = mfma16(af[mi], bfr[ni], acc[mi][ni]);
    }
    __syncthreads();
  }

  if (MODE == 0) {
#pragma unroll
    for (int mi = 0; mi < 4; ++mi) {
      int mbase = bm * 128 + wr * 64 + mi * 16 + 4 * g;
      int t = mbase >> 2;
#pragma unroll
      for (int ni = 0; ni < 4; ++ni) {
        int f = bn * 128 + wc * 64 + ni * 16 + cl;
        int sec = f / EDIM;
        int f0 = f - sec * EDIM;
        int h = f0 >> 6, d = f0 & 63;
        float bv = bias[f];
        float vals[4];
#pragma unroll
        for (int r = 0; r < 4; ++r) vals[r] = acc[mi][ni][r] + bv;
        if (sec < 2) {
          int j = d >> 1;
          float cv = ct[t * 32 + j], sv = st[t * 32 + j];
          bf16* dst = (sec == 0) ? qo : ko;
#pragma unroll
          for (int r = 0; r < 4; ++r) {
            float other = __shfl_xor(vals[r], 1);
            float rv = (d & 1) ? (vals[r] * cv + other * sv)
                               : (vals[r] * cv - other * sv);
            if (sec == 0) rv *= 0.125f * LOG2E;   // fold 1/sqrt(hd) and log2e
            dst[(((size_t)r * NH + h) * TLEN + t) * HD + d] = (bf16)rv;
          }
        } else {
#pragma unroll
          for (int r = 0; r < 4; ++r)
            vo[(((size_t)r * NH + h) * TLEN + t) * HD + d] = (bf16)vals[r];
        }
      }
    }
  } else {
#pragma unroll
    for (int mi = 0; mi < 4; ++mi) {
      int mbase = bm * 128 + wr * 64 + mi * 16 + 4 * g;
#pragma unroll
      for (int ni = 0; ni < 4; ++ni) {
        int n = bn * 128 + wc * 64 + ni * 16 + cl;
        float bv = bias[n];
#pragma unroll
        for (int r = 0; r < 4; ++r)
          fo[(size_t)(mbase + r) * EDIM + n] = acc[mi][ni][r] + bv;
      }
    }
  }
}

// ---------------- flash attention v5 ------------------------------------------
// Swapped QK^T (sc = mfma(K,Q)) -> lane owns q = cl: scalar running max/denom.
// P stays in registers with NO exchange: the PV k-dim uses the permutation
// sigma(8g+j) = 16*(j>=4) + 4g + (j&3), applied identically to the V^T
// A-operand (two 8B LDS reads per fragment) and the P B-operand (cvt_pk words
// in natural order) -- permutation cancels in the MFMA dot product.
// Denominator via all-ones A-frag MFMA; exp2-domain softmax.
__global__ __launch_bounds__(512) void attn_kernel(
    const bf16* __restrict__ qa, const bf16* __restrict__ ka,
    const bf16* __restrict__ vt, const float* __restrict__ mask,
    const uint* __restrict__ flags, bf16* __restrict__ xo) {
  __shared__ __align__(16) bf16 Ks[2][4096];
  __shared__ __align__(16) bf16 Vs[2][4096];
  int tid = threadIdx.x;
  int lane = tid & 63, w = tid >> 6;
  int g = lane >> 4, cl = lane & 15;
  int bh = blockIdx.y;
  int qrow0 = blockIdx.x * 128 + w * 16;
  const bf16* qbh = qa + (size_t)bh * TLEN * HD;
  const char* kbase = (const char*)(ka + (size_t)bh * TLEN * HD);
  const char* vbase = (const char*)(vt + (size_t)bh * HD * TLEN);
  int lrow = lane >> 3;
  int colb = ((lane & 7) ^ lrow) << 4;
  int sw = w & 3;              // staging sub-role: waves 0-3 K, 4-7 V^T
  const uint* flgrow = flags + (qrow0 >> 6) * 32;

  // hoisted Q fragments (0.125*log2e scale folded in at in_proj)
  bf16x8 qf[2];
#pragma unroll
  for (int h = 0; h < 2; ++h)
    qf[h] = *reinterpret_cast<const bf16x8*>(
        qbh + (size_t)(qrow0 + cl) * HD + h * 32 + g * 8);

  bf16x8 ones;
#pragma unroll
  for (int j = 0; j < 8; ++j) ones[j] = (bf16)1.0f;

  f32x4 o[4] = {};   // O^T: lane holds (d = di*16 + 4g + r, q = qrow0 + cl)
  f32x4 oden = {};   // softmax denominator (all 4 rows identical)
  float mrow = -1e30f;

  // prologue: stage tile 0 into buffer 0
#pragma unroll
  for (int i = 0; i < 2; ++i) {
    int qi = sw * 2 + i;
    int row = qi * 8 + lrow;
    if (w < 4)
      GLD16(kbase + (size_t)row * 128 + colb, &Ks[0][qi * 512 + lane * 8]);
    else
      GLD16(vbase + (size_t)row * (TLEN * 2) + colb, &Vs[0][qi * 512 + lane * 8]);
  }
  __syncthreads();

  for (int stile = 0; stile < TLEN / 64; ++stile) {
    int cur = stile & 1;
    // prefetch next tile into the other buffer (lands during compute)
    if (stile + 1 < TLEN / 64) {
      int s1 = (stile + 1) * 64;
#pragma unroll
      for (int i = 0; i < 2; ++i) {
        int qi = sw * 2 + i;
        int row = qi * 8 + lrow;
        if (w < 4)
          GLD16(kbase + (size_t)(s1 + row) * 128 + colb,
                &Ks[cur ^ 1][qi * 512 + lane * 8]);
        else
          GLD16(vbase + (size_t)row * (TLEN * 2) + s1 * 2 + colb,
                &Vs[cur ^ 1][qi * 512 + lane * 8]);
      }
    }
    const bf16* Kc = Ks[cur];
    const bf16* Vc = Vs[cur];

    // S^T = K Q^T : lane holds (s = stile*64 + ni*16 + 4g + r, q = qrow0 + cl)
    f32x4 sc[4];
#pragma unroll
    for (int ni = 0; ni < 4; ++ni) {
      bf16x8 k0 = ldsfrag(Kc, ni * 16 + cl, g * 16);
      bf16x8 k1 = ldsfrag(Kc, ni * 16 + cl, 64 + g * 16);
      f32x4 z = {};
      z = mfma16(k0, qf[0], z);
      z = mfma16(k1, qf[1], z);
      sc[ni] = z;
    }

    // mask add (log2 domain) only when the 64x64 mask tile has nonzeros
    if (flgrow[stile]) {
      int q = qrow0 + cl;
#pragma unroll
      for (int ni = 0; ni < 4; ++ni)
#pragma unroll
        for (int r = 0; r < 4; ++r)
          sc[ni][r] = fmaf(mask[(size_t)q * TLEN + stile * 64 + ni * 16 + 4 * g + r],
                           LOG2E, sc[ni][r]);
    }

    // defer-max (THR = 8*log2e): scalar per lane since q = cl is fixed
    float ml = fmaxf(fmaxf(fmaxf(sc[0][0], sc[0][1]), fmaxf(sc[0][2], sc[0][3])),
                     fmaxf(fmaxf(sc[1][0], sc[1][1]), fmaxf(sc[1][2], sc[1][3])));
    ml = fmaxf(ml,
               fmaxf(fmaxf(fmaxf(sc[2][0], sc[2][1]), fmaxf(sc[2][2], sc[2][3])),
                     fmaxf(fmaxf(sc[3][0], sc[3][1]), fmaxf(sc[3][2], sc[3][3]))));
    if (!__all(ml <= mrow + 11.54f)) {
      float mfull = fmaxf(ml, __shfl_xor(ml, 16));
      mfull = fmaxf(mfull, __shfl_xor(mfull, 32));
      float mn = fmaxf(mrow, mfull);
      float al = exp2f(mrow - mn);
      mrow = mn;
#pragma unroll
      for (int di = 0; di < 4; ++di)
#pragma unroll
        for (int r = 0; r < 4; ++r) o[di][r] *= al;
#pragma unroll
      for (int r = 0; r < 4; ++r) oden[r] *= al;
    }

    // P = exp2(S - m), pack to bf16 pairs. Under sigma, the B-fragments are
    // just the pk words in natural order: f0 = ni 0..1, f1 = ni 2..3.
    union { uint u[4]; bf16x8 v; } f0, f1;
#pragma unroll
    for (int ni = 0; ni < 4; ++ni) {
      float p0 = exp2f(sc[ni][0] - mrow);
      float p1 = exp2f(sc[ni][1] - mrow);
      float p2 = exp2f(sc[ni][2] - mrow);
      float p3 = exp2f(sc[ni][3] - mrow);
      uint lo = cvtpk(p0, p1);
      uint hi2 = cvtpk(p2, p3);
      if (ni < 2) { f0.u[2 * ni] = lo; f0.u[2 * ni + 1] = hi2; }
      else        { f1.u[2 * (ni - 2)] = lo; f1.u[2 * (ni - 2) + 1] = hi2; }
    }

    // O^T += V^T P with sigma-permuted k: A-side reads s = 4g+(0..3) and
    // 16+4g+(0..3) for f0 (bytes 8g, 32+8g); +32 elements for f1.
#pragma unroll
    for (int di = 0; di < 4; ++di) {
      int row = di * 16 + cl;
      union { uint2 h[2]; bf16x8 v; } va, vb;
      va.h[0] = ldsfrag64(Vc, row, 8 * g);
      va.h[1] = ldsfrag64(Vc, row, 32 + 8 * g);
      vb.h[0] = ldsfrag64(Vc, row, 64 + 8 * g);
      vb.h[1] = ldsfrag64(Vc, row, 96 + 8 * g);
      o[di] = mfma16(va.v, f0.v, o[di]);
      o[di] = mfma16(vb.v, f1.v, o[di]);
    }
    oden = mfma16(ones, f0.v, oden);
    oden = mfma16(ones, f1.v, oden);

    __syncthreads();   // prefetch drained + buffer-reuse protection
  }

  // epilogue: x[t*B+b][h*64+d], d = di*16 + 4g + r (r contiguous -> 8B stores)
  int b = bh / NH, h = bh % NH;
  int t = qrow0 + cl;
  float inv = 1.0f / oden[0];
  bf16* dst = xo + (size_t)(t * BSZ + b) * EDIM + h * HD + 4 * g;
#pragma unroll
  for (int di = 0; di < 4; ++di) {
    union { bf16 hh[4]; uint2 u; } w4;
#pragma unroll
    for (int r = 0; r < 4; ++r) w4.hh[r] = (bf16)(o[di][r] * inv);
    *reinterpret_cast<uint2*>(dst + di * 16) = w4.u;
  }
}

extern "C" void kernel_launch(void* const* d_in, const int* in_sizes, int n_in,
                              void* d_out, int out_size, void* d_ws, size_t ws_size,
                              hipStream_t stream) {
  const float* query = (const float*)d_in[0];
  const float* mask  = (const float*)d_in[1];
  const float* win   = (const float*)d_in[2];
  const float* bin   = (const float*)d_in[3];
  const float* wout  = (const float*)d_in[4];
  const float* bout  = (const float*)d_in[5];
  (void)in_sizes; (void)n_in; (void)out_size; (void)ws_size;

  char* ws = (char*)d_ws;
  float* ct   = (float*)(ws + CT_OFF);
  float* st   = (float*)(ws + ST_OFF);
  uint*  flg  = (uint*)(ws + FLG_OFF);
  bf16*  aq   = (bf16*)(ws + AQ_OFF);
  bf16*  vtb  = (bf16*)(ws + VT_OFF);   // reuses AQ region (AQ dead after gemm0)
  bf16*  qb   = (bf16*)(ws + QB_OFF);
  bf16*  kb   = (bf16*)(ws + KB_OFF);
  bf16*  vb   = (bf16*)(ws + VB_OFF);
  bf16*  xb   = (bf16*)(ws + XB_OFF);   // reuses VB region (VB dead after vtrans)
  bf16*  wib  = (bf16*)(ws + WI_OFF);
  bf16*  wob  = (bf16*)(ws + WO_OFF);
  float* out  = (float*)d_out;

  prep_all_kernel<<<dim3(5504), dim3(256), 0, stream>>>(
      query, aq, win, wib, wout, wob, mask, flg, ct, st);

  gemm_bt<0><<<dim3(3 * EDIM / 128, TLEN * BSZ / 128), dim3(256), 0, stream>>>(
      aq, wib, bin, ct, st, qb, kb, vb, nullptr);

  vtrans_kernel<<<dim3(TLEN / 256, NBH), dim3(256), 0, stream>>>(vb, vtb);

  attn_kernel<<<dim3(TLEN / 128, NBH), dim3(512), 0, stream>>>(
      qb, kb, vtb, mask, flg, xb);

  gemm_bt<1><<<dim3(EDIM / 128, TLEN * BSZ / 128), dim3(256), 0, stream>>>(
      xb, wob, bout, nullptr, nullptr, nullptr, nullptr, nullptr, out);
}

// Round 9
// 278.876 us; speedup vs baseline: 1.0398x; 1.0398x over previous
//
#include <hip/hip_runtime.h>
#include <math.h>

#define TLEN 2048
#define BSZ  4
#define EDIM 768
#define NH   12
#define HD   64
#define NBH  (BSZ * NH)
#define LOG2E 1.44269504088896f

typedef __bf16 bf16;
typedef __bf16 bf16x8 __attribute__((ext_vector_type(8)));
typedef float  f32x4  __attribute__((ext_vector_type(4)));
typedef unsigned int uint;

__device__ __forceinline__ f32x4 mfma16(bf16x8 a, bf16x8 b, f32x4 c) {
  return __builtin_amdgcn_mfma_f32_16x16x32_bf16(a, b, c, 0, 0, 0);
}

__device__ __forceinline__ uint cvtpk(float lo, float hi) {
  uint r;
  asm("v_cvt_pk_bf16_f32 %0, %1, %2" : "=v"(r) : "v"(lo), "v"(hi));
  return r;
}

// async global->LDS 16B (dest = wave-uniform base + lane*16; source per-lane)
#define GLD16(gp, lp)                                                          \
  __builtin_amdgcn_global_load_lds(                                            \
      (const __attribute__((address_space(1))) uint32_t*)(gp),                 \
      (__attribute__((address_space(3))) uint32_t*)(lp), 16, 0, 0)

// swizzled LDS fragment read: tile rows of 128B, XOR bits 4-6 with row&7
__device__ __forceinline__ bf16x8 ldsfrag(const bf16* t, int row, int kb) {
  return *reinterpret_cast<const bf16x8*>(
      (const char*)t + row * 128 + (kb ^ ((row & 7) << 4)));
}

// ---------------- workspace layout (bytes) ----------------
#define CT_OFF   0x0u
#define ST_OFF   0x40000u
#define FLG_OFF  0x80000u
#define AQ_OFF   0x100000u   // query bf16; reused as VT after gemm0
#define VT_OFF   0x100000u
#define QB_OFF   0xD00000u
#define KB_OFF   0x1900000u
#define VB_OFF   0x2500000u  // reused as XB after vtrans
#define XB_OFF   0x2500000u
#define WI_OFF   0x3100000u
#define WO_OFF   0x3460000u

#define QN8  786432   // 2048*4*768/8
#define WIN8 221184   // 2304*768/8
#define WON8 73728    // 768*768/8

__device__ __forceinline__ void cvt8(const float* __restrict__ s,
                                     bf16* __restrict__ d, int i) {
  const float4* sp = reinterpret_cast<const float4*>(s) + (size_t)i * 2;
  float4 a = sp[0], b = sp[1];
  bf16x8 o;
  o[0] = (bf16)a.x; o[1] = (bf16)a.y; o[2] = (bf16)a.z; o[3] = (bf16)a.w;
  o[4] = (bf16)b.x; o[5] = (bf16)b.y; o[6] = (bf16)b.z; o[7] = (bf16)b.w;
  reinterpret_cast<bf16x8*>(d)[i] = o;
}

// ---------------- fused prep: rope tables + fp32->bf16 cvt + mask flags -------
__global__ __launch_bounds__(256) void prep_all_kernel(
    const float* __restrict__ q, bf16* __restrict__ qo,
    const float* __restrict__ wi, bf16* __restrict__ wio,
    const float* __restrict__ wo, bf16* __restrict__ woo,
    const float* __restrict__ mask, uint* __restrict__ flags,
    float* __restrict__ ct, float* __restrict__ st) {
  int bid = blockIdx.x;
  int tid = threadIdx.x;
  if (bid < 256) {
    int i = bid * 256 + tid;               // TLEN*32 table entries
    int t = i >> 5, j = i & 31;
    double ang = (double)t * pow(10000.0, -(double)j / 32.0);
    st[i] = (float)sin(ang);
    ct[i] = (float)cos(ang);
  } else if (bid < 4480) {
    int i = (bid - 256) * 256 + tid;
    if (i < QN8) { cvt8(q, qo, i); return; }
    int j = i - QN8;
    if (j < WIN8) { cvt8(wi, wio, j); return; }
    cvt8(wo, woo, j - WIN8);
  } else {
    int tile = bid - 4480;                 // 0..1023
    int ty = tile >> 5, tx = tile & 31;
    uint acc = 0;
#pragma unroll
    for (int i = 0; i < 4; ++i) {
      int c = tid + 256 * i;
      int rr = c >> 4, cc = (c & 15) * 4;
      float4 v = *reinterpret_cast<const float4*>(
          mask + (size_t)(ty * 64 + rr) * TLEN + tx * 64 + cc);
      acc |= __float_as_uint(v.x) | __float_as_uint(v.y) |
             __float_as_uint(v.z) | __float_as_uint(v.w);
    }
    unsigned long long b = __ballot(acc != 0);
    __shared__ uint red[4];
    if ((tid & 63) == 0) red[tid >> 6] = (b != 0ull) ? 1u : 0u;
    __syncthreads();
    if (tid == 0) flags[tile] = red[0] | red[1] | red[2] | red[3];
  }
}

// ---------------- V transpose: [bh][t][d] -> [bh][d][tile][tau(s)] ------------
// Each 64-s tile stored interleaved: position p holds s = 16*(p>>2 & 1 ...)
// precisely: p(s) = 32*((s>>5)&1) + 8*((s>>2)&3) + 4*((s>>4)&1) + (s&3), so a
// natural 16B LDS read at byte 16g yields s-slots sigma(8g+j)=16*(j>=4)+4g+(j&3)
// matching the in-register P fragment order (k-permutation cancels in MFMA).
__global__ __launch_bounds__(256) void vtrans_kernel(const bf16* __restrict__ v,
                                                     bf16* __restrict__ vt) {
  int w = threadIdx.x >> 6, lane = threadIdx.x & 63;
  int bh = blockIdx.y;
  int t0 = (blockIdx.x * 4 + w) * 64;
  const bf16* src = v + ((size_t)bh * TLEN + t0) * HD;
  bf16* dst = vt + (size_t)bh * HD * TLEN + t0;   // tile base (64-aligned)
  int d0 = (lane & 7) * 8, a = lane >> 3;         // t-range = 8a..8a+7
  bf16x8 in[8];
#pragma unroll
  for (int r = 0; r < 8; ++r)
    in[r] = *reinterpret_cast<const bf16x8*>(src + (size_t)(8 * a + r) * HD + d0);
  int p0 = 32 * (a >> 2) + 8 * ((2 * a) & 3) + 4 * ((a >> 1) & 1);
  int p1 = 32 * (a >> 2) + 8 * ((2 * a + 1) & 3) + 4 * ((a >> 1) & 1);
#pragma unroll
  for (int j = 0; j < 8; ++j) {
    union { bf16 h[4]; uint2 u; } w0, w1;
#pragma unroll
    for (int r = 0; r < 4; ++r) { w0.h[r] = in[r][j]; w1.h[r] = in[r + 4][j]; }
    bf16* rowp = dst + (size_t)(d0 + j) * TLEN;
    *reinterpret_cast<uint2*>(rowp + p0) = w0.u;
    *reinterpret_cast<uint2*>(rowp + p1) = w1.u;
  }
}

// ---------------- GEMM C = A * B^T (+bias), bf16 in, 128x128 tile, BK=64 ------
template <int MODE>
__global__ __launch_bounds__(256) void gemm_bt(
    const bf16* __restrict__ A, const bf16* __restrict__ B,
    const float* __restrict__ bias,
    const float* __restrict__ ct, const float* __restrict__ st,
    bf16* __restrict__ qo, bf16* __restrict__ ko, bf16* __restrict__ vo,
    float* __restrict__ fo) {
  constexpr int K = EDIM;
  __shared__ __align__(16) bf16 As[128 * 64];
  __shared__ __align__(16) bf16 Bs[128 * 64];
  int tid = threadIdx.x;
  int lane = tid & 63, w = tid >> 6;
  int wr = w >> 1, wc = w & 1;
  int g = lane >> 4, cl = lane & 15;
  int bm = blockIdx.y, bn = blockIdx.x;
  int lrow = lane >> 3;
  int colb = ((lane & 7) ^ lrow) << 4;
  const char* Abase = (const char*)(A + (size_t)bm * 128 * K);
  const char* Bbase = (const char*)(B + (size_t)bn * 128 * K);

  f32x4 acc[4][4] = {};

  for (int kt = 0; kt < K; kt += 64) {
#pragma unroll
    for (int i = 0; i < 4; ++i) {
      int qi = w * 4 + i;
      int row = qi * 8 + lrow;
      GLD16(Abase + (size_t)row * (K * 2) + kt * 2 + colb, As + qi * 512 + lane * 8);
      GLD16(Bbase + (size_t)row * (K * 2) + kt * 2 + colb, Bs + qi * 512 + lane * 8);
    }
    __syncthreads();
#pragma unroll
    for (int kk = 0; kk < 2; ++kk) {
      bf16x8 af[4], bfr[4];
#pragma unroll
      for (int mi = 0; mi < 4; ++mi)
        af[mi] = ldsfrag(As, wr * 64 + mi * 16 + cl, kk * 64 + g * 16);
#pragma unroll
      for (int ni = 0; ni < 4; ++ni)
        bfr[ni] = ldsfrag(Bs, wc * 64 + ni * 16 + cl, kk * 64 + g * 16);
#pragma unroll
      for (int mi = 0; mi < 4; ++mi)
#pragma unroll
        for (int ni = 0; ni < 4; ++ni)
          acc[mi][ni] = mfma16(af[mi], bfr[ni], acc[mi][ni]);
    }
    __syncthreads();
  }

  if (MODE == 0) {
#pragma unroll
    for (int mi = 0; mi < 4; ++mi) {
      int mbase = bm * 128 + wr * 64 + mi * 16 + 4 * g;
      int t = mbase >> 2;
#pragma unroll
      for (int ni = 0; ni < 4; ++ni) {
        int f = bn * 128 + wc * 64 + ni * 16 + cl;
        int sec = f / EDIM;
        int f0 = f - sec * EDIM;
        int h = f0 >> 6, d = f0 & 63;
        float bv = bias[f];
        float vals[4];
#pragma unroll
        for (int r = 0; r < 4; ++r) vals[r] = acc[mi][ni][r] + bv;
        if (sec < 2) {
          int j = d >> 1;
          float cv = ct[t * 32 + j], sv = st[t * 32 + j];
          bf16* dst = (sec == 0) ? qo : ko;
#pragma unroll
          for (int r = 0; r < 4; ++r) {
            float other = __shfl_xor(vals[r], 1);
            float rv = (d & 1) ? (vals[r] * cv + other * sv)
                               : (vals[r] * cv - other * sv);
            if (sec == 0) rv *= 0.125f * LOG2E;   // fold 1/sqrt(hd) and log2e
            dst[(((size_t)r * NH + h) * TLEN + t) * HD + d] = (bf16)rv;
          }
        } else {
#pragma unroll
          for (int r = 0; r < 4; ++r)
            vo[(((size_t)r * NH + h) * TLEN + t) * HD + d] = (bf16)vals[r];
        }
      }
    }
  } else {
#pragma unroll
    for (int mi = 0; mi < 4; ++mi) {
      int mbase = bm * 128 + wr * 64 + mi * 16 + 4 * g;
#pragma unroll
      for (int ni = 0; ni < 4; ++ni) {
        int n = bn * 128 + wc * 64 + ni * 16 + cl;
        float bv = bias[n];
#pragma unroll
        for (int r = 0; r < 4; ++r)
          fo[(size_t)(mbase + r) * EDIM + n] = acc[mi][ni][r] + bv;
      }
    }
  }
}

// ---------------- flash attention v6 ------------------------------------------
// Swapped QK^T (sc = mfma(K,Q)) -> lane owns q = cl: scalar running max/denom.
// P stays in registers; PV k-permutation sigma is baked into the vt array
// (tau-interleaved tiles), so BOTH V (16B conflict-free ldsfrag) and P (natural
// cvt_pk order) need no reordering. Denominator via all-ones A-frag MFMA.
// XCD-aware block swizzle: each XCD owns 6 whole heads -> K/V L2-resident.
__global__ __launch_bounds__(512) void attn_kernel(
    const bf16* __restrict__ qa, const bf16* __restrict__ ka,
    const bf16* __restrict__ vt, const float* __restrict__ mask,
    const uint* __restrict__ flags, bf16* __restrict__ xo) {
  __shared__ __align__(16) bf16 Ks[2][4096];
  __shared__ __align__(16) bf16 Vs[2][4096];
  int tid = threadIdx.x;
  int lane = tid & 63, w = tid >> 6;
  int g = lane >> 4, cl = lane & 15;
  // bijective XCD swizzle (grid = 16 x 48 = 768, 768%8==0): XCD x gets 6 heads
  int lin = blockIdx.y * 16 + blockIdx.x;
  int lin2 = (lin & 7) * 96 + (lin >> 3);
  int qt = lin2 & 15, bh = lin2 >> 4;
  int qrow0 = qt * 128 + w * 16;
  const bf16* qbh = qa + (size_t)bh * TLEN * HD;
  const char* kbase = (const char*)(ka + (size_t)bh * TLEN * HD);
  const char* vbase = (const char*)(vt + (size_t)bh * HD * TLEN);
  int lrow = lane >> 3;
  int colb = ((lane & 7) ^ lrow) << 4;
  int sw = w & 3;              // staging sub-role: waves 0-3 K, 4-7 V^T
  const uint* flgrow = flags + (qrow0 >> 6) * 32;

  // hoisted Q fragments (0.125*log2e scale folded in at in_proj)
  bf16x8 qf[2];
#pragma unroll
  for (int h = 0; h < 2; ++h)
    qf[h] = *reinterpret_cast<const bf16x8*>(
        qbh + (size_t)(qrow0 + cl) * HD + h * 32 + g * 8);

  bf16x8 ones;
#pragma unroll
  for (int j = 0; j < 8; ++j) ones[j] = (bf16)1.0f;

  f32x4 o[4] = {};   // O^T: lane holds (d = di*16 + 4g + r, q = qrow0 + cl)
  f32x4 oden = {};   // softmax denominator (all 4 rows identical)
  float mrow = -1e30f;

  // prologue: stage tile 0 into buffer 0
#pragma unroll
  for (int i = 0; i < 2; ++i) {
    int qi = sw * 2 + i;
    int row = qi * 8 + lrow;
    if (w < 4)
      GLD16(kbase + (size_t)row * 128 + colb, &Ks[0][qi * 512 + lane * 8]);
    else
      GLD16(vbase + (size_t)row * (TLEN * 2) + colb, &Vs[0][qi * 512 + lane * 8]);
  }
  __syncthreads();

  for (int stile = 0; stile < TLEN / 64; ++stile) {
    int cur = stile & 1;
    // prefetch next tile into the other buffer (lands during compute)
    if (stile + 1 < TLEN / 64) {
      int s1 = (stile + 1) * 64;
#pragma unroll
      for (int i = 0; i < 2; ++i) {
        int qi = sw * 2 + i;
        int row = qi * 8 + lrow;
        if (w < 4)
          GLD16(kbase + (size_t)(s1 + row) * 128 + colb,
                &Ks[cur ^ 1][qi * 512 + lane * 8]);
        else
          GLD16(vbase + (size_t)row * (TLEN * 2) + s1 * 2 + colb,
                &Vs[cur ^ 1][qi * 512 + lane * 8]);
      }
    }
    const bf16* Kc = Ks[cur];
    const bf16* Vc = Vs[cur];

    // S^T = K Q^T : lane holds (s = stile*64 + ni*16 + 4g + r, q = qrow0 + cl)
    f32x4 sc[4];
#pragma unroll
    for (int ni = 0; ni < 4; ++ni) {
      bf16x8 k0 = ldsfrag(Kc, ni * 16 + cl, g * 16);
      bf16x8 k1 = ldsfrag(Kc, ni * 16 + cl, 64 + g * 16);
      f32x4 z = {};
      z = mfma16(k0, qf[0], z);
      z = mfma16(k1, qf[1], z);
      sc[ni] = z;
    }

    // mask add (log2 domain) only when the 64x64 mask tile has nonzeros
    if (flgrow[stile]) {
      int q = qrow0 + cl;
#pragma unroll
      for (int ni = 0; ni < 4; ++ni)
#pragma unroll
        for (int r = 0; r < 4; ++r)
          sc[ni][r] = fmaf(mask[(size_t)q * TLEN + stile * 64 + ni * 16 + 4 * g + r],
                           LOG2E, sc[ni][r]);
    }

    // defer-max (THR = 8*log2e): scalar per lane since q = cl is fixed
    float ml = fmaxf(fmaxf(fmaxf(sc[0][0], sc[0][1]), fmaxf(sc[0][2], sc[0][3])),
                     fmaxf(fmaxf(sc[1][0], sc[1][1]), fmaxf(sc[1][2], sc[1][3])));
    ml = fmaxf(ml,
               fmaxf(fmaxf(fmaxf(sc[2][0], sc[2][1]), fmaxf(sc[2][2], sc[2][3])),
                     fmaxf(fmaxf(sc[3][0], sc[3][1]), fmaxf(sc[3][2], sc[3][3]))));
    if (!__all(ml <= mrow + 11.54f)) {
      float mfull = fmaxf(ml, __shfl_xor(ml, 16));
      mfull = fmaxf(mfull, __shfl_xor(mfull, 32));
      float mn = fmaxf(mrow, mfull);
      float al = exp2f(mrow - mn);
      mrow = mn;
#pragma unroll
      for (int di = 0; di < 4; ++di)
#pragma unroll
        for (int r = 0; r < 4; ++r) o[di][r] *= al;
#pragma unroll
      for (int r = 0; r < 4; ++r) oden[r] *= al;
    }

    // P = exp2(S - m), pack to bf16 pairs; fragment = pk words in natural
    // order (the sigma permutation lives in the vt layout).
    union { uint u[4]; bf16x8 v; } f0, f1;
#pragma unroll
    for (int ni = 0; ni < 4; ++ni) {
      float p0 = exp2f(sc[ni][0] - mrow);
      float p1 = exp2f(sc[ni][1] - mrow);
      float p2 = exp2f(sc[ni][2] - mrow);
      float p3 = exp2f(sc[ni][3] - mrow);
      uint lo = cvtpk(p0, p1);
      uint hi2 = cvtpk(p2, p3);
      if (ni < 2) { f0.u[2 * ni] = lo; f0.u[2 * ni + 1] = hi2; }
      else        { f1.u[2 * (ni - 2)] = lo; f1.u[2 * (ni - 2) + 1] = hi2; }
    }

    // O^T += V^T P : plain 16B fragments (conflict-free, same pattern as K)
#pragma unroll
    for (int di = 0; di < 4; ++di) {
      int row = di * 16 + cl;
      bf16x8 v0 = ldsfrag(Vc, row, g * 16);
      bf16x8 v1 = ldsfrag(Vc, row, 64 + g * 16);
      o[di] = mfma16(v0, f0.v, o[di]);
      o[di] = mfma16(v1, f1.v, o[di]);
    }
    oden = mfma16(ones, f0.v, oden);
    oden = mfma16(ones, f1.v, oden);

    __syncthreads();   // prefetch drained + buffer-reuse protection
  }

  // epilogue: x[t*B+b][h*64+d], d = di*16 + 4g + r (r contiguous -> 8B stores)
  int b = bh / NH, h = bh % NH;
  int t = qrow0 + cl;
  float inv = 1.0f / oden[0];
  bf16* dst = xo + (size_t)(t * BSZ + b) * EDIM + h * HD + 4 * g;
#pragma unroll
  for (int di = 0; di < 4; ++di) {
    union { bf16 hh[4]; uint2 u; } w4;
#pragma unroll
    for (int r = 0; r < 4; ++r) w4.hh[r] = (bf16)(o[di][r] * inv);
    *reinterpret_cast<uint2*>(dst + di * 16) = w4.u;
  }
}

extern "C" void kernel_launch(void* const* d_in, const int* in_sizes, int n_in,
                              void* d_out, int out_size, void* d_ws, size_t ws_size,
                              hipStream_t stream) {
  const float* query = (const float*)d_in[0];
  const float* mask  = (const float*)d_in[1];
  const float* win   = (const float*)d_in[2];
  const float* bin   = (const float*)d_in[3];
  const float* wout  = (const float*)d_in[4];
  const float* bout  = (const float*)d_in[5];
  (void)in_sizes; (void)n_in; (void)out_size; (void)ws_size;

  char* ws = (char*)d_ws;
  float* ct   = (float*)(ws + CT_OFF);
  float* st   = (float*)(ws + ST_OFF);
  uint*  flg  = (uint*)(ws + FLG_OFF);
  bf16*  aq   = (bf16*)(ws + AQ_OFF);
  bf16*  vtb  = (bf16*)(ws + VT_OFF);   // reuses AQ region (AQ dead after gemm0)
  bf16*  qb   = (bf16*)(ws + QB_OFF);
  bf16*  kb   = (bf16*)(ws + KB_OFF);
  bf16*  vb   = (bf16*)(ws + VB_OFF);
  bf16*  xb   = (bf16*)(ws + XB_OFF);   // reuses VB region (VB dead after vtrans)
  bf16*  wib  = (bf16*)(ws + WI_OFF);
  bf16*  wob  = (bf16*)(ws + WO_OFF);
  float* out  = (float*)d_out;

  prep_all_kernel<<<dim3(5504), dim3(256), 0, stream>>>(
      query, aq, win, wib, wout, wob, mask, flg, ct, st);

  gemm_bt<0><<<dim3(3 * EDIM / 128, TLEN * BSZ / 128), dim3(256), 0, stream>>>(
      aq, wib, bin, ct, st, qb, kb, vb, nullptr);

  vtrans_kernel<<<dim3(TLEN / 256, NBH), dim3(256), 0, stream>>>(vb, vtb);

  attn_kernel<<<dim3(TLEN / 128, NBH), dim3(512), 0, stream>>>(
      qb, kb, vtb, mask, flg, xb);

  gemm_bt<1><<<dim3(EDIM / 128, TLEN * BSZ / 128), dim3(256), 0, stream>>>(
      xb, wob, bout, nullptr, nullptr, nullptr, nullptr, nullptr, out);
}